// Round 7
// baseline (384.971 us; speedup 1.0000x reference)
//
#include <hip/hip_runtime.h>
#include <hip/hip_cooperative_groups.h>

namespace cg = cooperative_groups;

// ---------------------------------------------------------------------------
// BatchedGraphSAGE fused cooperative kernel, with multi-kernel fallback.
// mean(gather(x)) @ W^T == mean(gather(x @ W^T)): project once, gather the
// 2 MB bf16 projected tensor (L2-resident).
// Coop path (1 dispatch): Phase A GEMM -> xWx/xWn; grid.sync; Phase B gather+
// l2norm+relu, h kept in LDS as bf16, BN partials -> 16 replicated atomic
// buffers; grid.sync; Phase C coef fold + apply.
// LDS = 9.5 KB/block (hl bf16 + lidx) so the cooperative occupancy check
// passes under any LDS-per-CU model (r6 failed: 34 KB -> launch rejected,
// output stayed zero; absmax matched the round-0 stub exactly).
// Fallback path (r5's proven 5-kernel pipeline) if coop launch errors.
// ---------------------------------------------------------------------------

typedef short  s16x8 __attribute__((ext_vector_type(8)));
typedef float  f32x4 __attribute__((ext_vector_type(4)));
typedef unsigned short u16x4 __attribute__((ext_vector_type(4)));

#define NREP 16

// ws layout (bytes)
#define OFF_XWX    (0u)            // xWx  [4096][256] bf16 : 2 MB (bias added)
#define OFF_XWN    (2097152u)      // xWn  [4096][256] bf16 : 2 MB
#define OFF_SUMS   (4194304u)      // sums [16][2048] f32   : 128 KB
// fallback-only:
#define OFF_WCAT   (5242880u)      // Wcat [512][256] bf16  : 256 KB
#define OFF_HBUF   (6291456u)      // h    [4096][1024] bf16: 8 MB
#define OFF_COEFA  (14680064u)     // A[1024] f32
#define OFF_COEFB  (14684160u)     // B[1024] f32

__device__ __forceinline__ unsigned short f2bf(float f) {
    unsigned int u = __float_as_uint(f);
    u = (u + 0x7FFFu + ((u >> 16) & 1u)) >> 16;          // RNE
    return (unsigned short)u;
}
__device__ __forceinline__ float bflo(unsigned int d) {
    return __uint_as_float(d << 16);
}
__device__ __forceinline__ float bfhi(unsigned int d) {
    return __uint_as_float(d & 0xFFFF0000u);
}
__device__ __forceinline__ float bf2f(unsigned short h) {
    return __uint_as_float(((unsigned int)h) << 16);
}
__device__ __forceinline__ s16x8 cvt_frag(const float* p) {
    float4 a0 = *(const float4*)p;
    float4 a1 = *(const float4*)(p + 4);
    s16x8 a;
    a[0]=(short)f2bf(a0.x); a[1]=(short)f2bf(a0.y);
    a[2]=(short)f2bf(a0.z); a[3]=(short)f2bf(a0.w);
    a[4]=(short)f2bf(a1.x); a[5]=(short)f2bf(a1.y);
    a[6]=(short)f2bf(a1.z); a[7]=(short)f2bf(a1.w);
    return a;
}

// ========================= fused cooperative kernel ========================
__global__ __launch_bounds__(256, 4) void fused_sage(
    const float* __restrict__ x,
    const int* __restrict__ idx1, const int* __restrict__ idx2,
    const int* __restrict__ idx3,
    const float* __restrict__ Wx, const float* __restrict__ bx,
    const float* __restrict__ Wn, const float* __restrict__ bn,
    const float* __restrict__ gamma, const float* __restrict__ beta,
    unsigned short* __restrict__ xWx, unsigned short* __restrict__ xWn,
    float* __restrict__ sums, float* __restrict__ out)
{
    __shared__ int lidx[4][96];                       // 1.5 KB
    __shared__ unsigned short hl[4][1024];            // 8 KB; A reuses as stage
    const int t = threadIdx.x, w = t >> 6, l = t & 63;
    const int l15 = l & 15, lhi = l >> 4;
    const int bid = blockIdx.x;

    // ---- Phase A: GEMM, 64 rows x 32 cols per block (1024 blocks) --------
    {
        const int rowTile = bid >> 4;                 // 0..63
        const int colTile = bid & 15;                 // 0..15
        const int rowBase = rowTile * 64 + w * 16;
        const int colBase = colTile * 32;
        const bool isX = (colTile < 8);
        const float* Wmat = isX ? Wx : Wn;
        const int wrow0 = colBase - (isX ? 0 : 256);  // 0..224 within Wmat

        f32x4 acc[2] = {};
        const float* ap  = &x[(rowBase + l15) * 256 + lhi * 8];
        const float* wp0 = &Wmat[(wrow0 +      l15) * 256 + lhi * 8];
        const float* wp1 = &Wmat[(wrow0 + 16 + l15) * 256 + lhi * 8];
        #pragma unroll
        for (int kk = 0; kk < 256; kk += 32) {
            s16x8 a  = cvt_frag(ap  + kk);
            s16x8 b0 = cvt_frag(wp0 + kk);
            s16x8 b1 = cvt_frag(wp1 + kk);
            acc[0] = __builtin_amdgcn_mfma_f32_16x16x32_bf16(a, b0, acc[0], 0, 0, 0);
            acc[1] = __builtin_amdgcn_mfma_f32_16x16x32_bf16(a, b1, acc[1], 0, 0, 0);
        }
        if (bid < NREP) {                             // zero BN partials
            float4 z = {0.f, 0.f, 0.f, 0.f};
            *(float4*)&sums[bid * 2048 + t * 4]        = z;
            *(float4*)&sums[bid * 2048 + 1024 + t * 4] = z;
        }
        // stage tile (bf16) in LDS, then coalesced 16B global writes
        unsigned short* stage = &hl[0][0];            // 64x32 shorts = 4 KB
        const int row0l = w * 16 + lhi * 4;
        #pragma unroll
        for (int c = 0; c < 2; ++c) {
            float badd = isX ? bx[colBase + c * 16 + l15] : 0.f;
            #pragma unroll
            for (int r = 0; r < 4; ++r)
                stage[(row0l + r) * 32 + c * 16 + l15] = f2bf(acc[c][r] + badd);
        }
        __syncthreads();
        {
            const int rl = t >> 2, seg = t & 3;
            uint4 v = *(const uint4*)&stage[rl * 32 + seg * 8];
            unsigned short* dst = isX ? xWx : xWn;
            *(uint4*)&dst[(rowTile * 64 + rl) * 256 + wrow0 + seg * 8] = v;
        }
    }
    cg::this_grid().sync();

    // ---- Phase B: gather + l2norm + relu; h -> LDS bf16; BN partials -----
    {
        const int r = bid * 4 + w;
        const int b = r >> 9, n = r & 511;
        if (l < 32) {
            lidx[w][l]      = idx1[n * 32 + l];
            lidx[w][64 + l] = idx3[n * 32 + l];
        } else {
            lidx[w][l]      = idx2[n * 32 + (l & 31)];
        }
        __syncthreads();

        const float4 bnv = *(const float4*)&bn[l * 4];
        const unsigned short* basep = &xWn[(unsigned)b * (512u * 256u)];
        f32x4 m1 = {}, m2 = {}, m3 = {};
        #pragma unroll
        for (int k = 0; k < 32; ++k) {
            uint2 d = *(const uint2*)(basep + lidx[w][k] * 256 + l * 4);
            m1[0] += bflo(d.x); m1[1] += bfhi(d.x);
            m1[2] += bflo(d.y); m1[3] += bfhi(d.y);
        }
        #pragma unroll
        for (int k = 0; k < 32; ++k) {
            uint2 d = *(const uint2*)(basep + lidx[w][32 + k] * 256 + l * 4);
            m2[0] += bflo(d.x); m2[1] += bfhi(d.x);
            m2[2] += bflo(d.y); m2[3] += bfhi(d.y);
        }
        #pragma unroll
        for (int k = 0; k < 32; ++k) {
            uint2 d = *(const uint2*)(basep + lidx[w][64 + k] * 256 + l * 4);
            m3[0] += bflo(d.x); m3[1] += bfhi(d.x);
            m3[2] += bflo(d.y); m3[3] += bfhi(d.y);
        }

        uint2 hd = *(const uint2*)(xWx + r * 256 + l * 4);   // bias pre-added
        f32x4 hseg[4];
        hseg[0][0] = bflo(hd.x); hseg[0][1] = bfhi(hd.x);
        hseg[0][2] = bflo(hd.y); hseg[0][3] = bfhi(hd.y);
        #pragma unroll
        for (int j = 0; j < 4; ++j) {
            hseg[1][j] = m1[j] * (1.f / 32.f) + bnv[j];
            hseg[2][j] = m2[j] * (1.f / 32.f) + bnv[j];
            hseg[3][j] = m3[j] * (1.f / 32.f) + bnv[j];
        }
        float p = 0.f;
        #pragma unroll
        for (int s = 0; s < 4; ++s)
            #pragma unroll
            for (int j = 0; j < 4; ++j) p += hseg[s][j] * hseg[s][j];
        #pragma unroll
        for (int m = 32; m > 0; m >>= 1) p += __shfl_xor(p, m);
        const float invn = 1.0f / fmaxf(sqrtf(p), 1e-12f);

        #pragma unroll
        for (int s = 0; s < 4; ++s) {
            float v0 = fmaxf(hseg[s][0] * invn, 0.f);
            float v1 = fmaxf(hseg[s][1] * invn, 0.f);
            float v2 = fmaxf(hseg[s][2] * invn, 0.f);
            float v3 = fmaxf(hseg[s][3] * invn, 0.f);
            uint2 o;
            o.x = (unsigned)f2bf(v0) | ((unsigned)f2bf(v1) << 16);
            o.y = (unsigned)f2bf(v2) | ((unsigned)f2bf(v3) << 16);
            *(uint2*)(&hl[w][s * 256 + l * 4]) = o;
        }
        __syncthreads();
        // fold 4 waves' h into BN partial sums; 8 atomics/thread
        float* sb = &sums[(bid & (NREP - 1)) * 2048];
        #pragma unroll
        for (int i = 0; i < 4; ++i) {
            const int c = t + i * 256;
            float sAc = 0.f, sQc = 0.f;
            #pragma unroll
            for (int w2 = 0; w2 < 4; ++w2) {
                float v = bf2f(hl[w2][c]);
                sAc += v; sQc += v * v;
            }
            atomicAdd(&sb[c], sAc);
            atomicAdd(&sb[1024 + c], sQc);
        }
    }
    cg::this_grid().sync();

    // ---- Phase C: coef fold + BN apply -----------------------------------
    {
        const int c0 = t * 4;
        float4 g  = *(const float4*)&gamma[c0];
        float4 be = *(const float4*)&beta[c0];
        f32x4 s = {}, q = {};
        #pragma unroll
        for (int rep = 0; rep < NREP; ++rep) {
            float4 a  = *(const float4*)&sums[rep * 2048 + c0];
            float4 b2 = *(const float4*)&sums[rep * 2048 + 1024 + c0];
            s[0] += a.x;  s[1] += a.y;  s[2] += a.z;  s[3] += a.w;
            q[0] += b2.x; q[1] += b2.y; q[2] += b2.z; q[3] += b2.w;
        }
        const float gg[4] = {g.x, g.y, g.z, g.w};
        const float bb[4] = {be.x, be.y, be.z, be.w};
        f32x4 A, Bc;
        #pragma unroll
        for (int j = 0; j < 4; ++j) {
            float mu  = s[j] * (1.f / 4096.f);
            float var = q[j] * (1.f / 4096.f) - mu * mu;
            A[j]  = gg[j] / sqrtf(var + 1e-5f);
            Bc[j] = bb[j] - mu * A[j];
        }
        #pragma unroll
        for (int w2 = 0; w2 < 4; ++w2) {
            uint2 hd = *(const uint2*)(&hl[w2][c0]);
            float4 o;
            o.x = bflo(hd.x) * A[0] + Bc[0];
            o.y = bfhi(hd.x) * A[1] + Bc[1];
            o.z = bflo(hd.y) * A[2] + Bc[2];
            o.w = bfhi(hd.y) * A[3] + Bc[3];
            *(float4*)&out[(unsigned)(bid * 4 + w2) * 1024u + c0] = o;
        }
    }
}

// ========================= fallback pipeline (r5, proven) ==================
__global__ __launch_bounds__(256) void k0_convert(
    const float* __restrict__ Wx, const float* __restrict__ Wn,
    unsigned short* __restrict__ Wcat)
{
    int e = (blockIdx.x * 256 + threadIdx.x) * 4;
    const float* src = (e < 65536) ? &Wx[e] : &Wn[e - 65536];
    float4 v = *(const float4*)src;
    u16x4 o; o[0]=f2bf(v.x); o[1]=f2bf(v.y); o[2]=f2bf(v.z); o[3]=f2bf(v.w);
    *(u16x4*)&Wcat[e] = o;
}

__global__ __launch_bounds__(256) void k1_gemm(
    const float* __restrict__ x, const unsigned short* __restrict__ W,
    const float* __restrict__ bx,
    unsigned short* __restrict__ xWx, unsigned short* __restrict__ xWn)
{
    const int tid = threadIdx.x;
    const int w = tid >> 6, l = tid & 63;
    const int l15 = l & 15, lhi = l >> 4;
    const int rowBase = blockIdx.x * 64 + w * 16;
    const int colBase = blockIdx.y * 64;

    f32x4 acc[4] = {};
    const float*          ap = &x[(rowBase + l15) * 256 + lhi * 8];
    const unsigned short* wp = &W[(colBase + l15) * 256 + lhi * 8];
    #pragma unroll
    for (int kk = 0; kk < 256; kk += 32) {
        s16x8 a = cvt_frag(ap + kk);
        #pragma unroll
        for (int c = 0; c < 4; ++c) {
            s16x8 b = *(const s16x8*)(wp + c * 16 * 256 + kk);
            acc[c] = __builtin_amdgcn_mfma_f32_16x16x32_bf16(a, b, acc[c], 0, 0, 0);
        }
    }
    const int row0 = rowBase + lhi * 4;
    if (colBase < 256) {
        #pragma unroll
        for (int c = 0; c < 4; ++c) {
            float bxv = bx[colBase + c * 16 + l15];
            #pragma unroll
            for (int r = 0; r < 4; ++r)
                xWx[(row0 + r) * 256 + colBase + c * 16 + l15] = f2bf(acc[c][r] + bxv);
        }
    } else {
        #pragma unroll
        for (int c = 0; c < 4; ++c)
            #pragma unroll
            for (int r = 0; r < 4; ++r)
                xWn[(row0 + r) * 256 + (colBase - 256) + c * 16 + l15] = f2bf(acc[c][r]);
    }
}

__global__ __launch_bounds__(256) void k2_rows(
    const unsigned short* __restrict__ xWx, const unsigned short* __restrict__ xWn,
    const int* __restrict__ idx1, const int* __restrict__ idx2,
    const int* __restrict__ idx3, const float* __restrict__ bn,
    unsigned short* __restrict__ hbuf, float* __restrict__ sums)
{
    __shared__ int   lidx[4][96];
    __shared__ float lpart[4][2048];
    const int t = threadIdx.x, w = t >> 6, l = t & 63;
    const int r = blockIdx.x * 4 + w;
    const int b = r >> 9, n = r & 511;

    if (l < 32) {
        lidx[w][l]      = idx1[n * 32 + l];
        lidx[w][64 + l] = idx3[n * 32 + l];
    } else {
        lidx[w][l]      = idx2[n * 32 + (l & 31)];
    }
    __syncthreads();

    const float4 bnv = *(const float4*)&bn[l * 4];
    const unsigned short* basep = &xWn[(unsigned)b * (512u * 256u)];
    f32x4 m1 = {}, m2 = {}, m3 = {};
    #pragma unroll
    for (int k = 0; k < 32; ++k) {
        uint2 d = *(const uint2*)(basep + lidx[w][k] * 256 + l * 4);
        m1[0] += bflo(d.x); m1[1] += bfhi(d.x);
        m1[2] += bflo(d.y); m1[3] += bfhi(d.y);
    }
    #pragma unroll
    for (int k = 0; k < 32; ++k) {
        uint2 d = *(const uint2*)(basep + lidx[w][32 + k] * 256 + l * 4);
        m2[0] += bflo(d.x); m2[1] += bfhi(d.x);
        m2[2] += bflo(d.y); m2[3] += bfhi(d.y);
    }
    #pragma unroll
    for (int k = 0; k < 32; ++k) {
        uint2 d = *(const uint2*)(basep + lidx[w][64 + k] * 256 + l * 4);
        m3[0] += bflo(d.x); m3[1] += bfhi(d.x);
        m3[2] += bflo(d.y); m3[3] += bfhi(d.y);
    }

    uint2 hd = *(const uint2*)(xWx + r * 256 + l * 4);
    f32x4 hseg[4];
    hseg[0][0] = bflo(hd.x); hseg[0][1] = bfhi(hd.x);
    hseg[0][2] = bflo(hd.y); hseg[0][3] = bfhi(hd.y);
    #pragma unroll
    for (int j = 0; j < 4; ++j) {
        hseg[1][j] = m1[j] * (1.f / 32.f) + bnv[j];
        hseg[2][j] = m2[j] * (1.f / 32.f) + bnv[j];
        hseg[3][j] = m3[j] * (1.f / 32.f) + bnv[j];
    }
    float p = 0.f;
    #pragma unroll
    for (int s = 0; s < 4; ++s)
        #pragma unroll
        for (int j = 0; j < 4; ++j) p += hseg[s][j] * hseg[s][j];
    #pragma unroll
    for (int m = 32; m > 0; m >>= 1) p += __shfl_xor(p, m);
    const float invn = 1.0f / fmaxf(sqrtf(p), 1e-12f);

    unsigned short* hr = &hbuf[(unsigned)r * 1024u];
    #pragma unroll
    for (int s = 0; s < 4; ++s) {
        f32x4 v;
        #pragma unroll
        for (int j = 0; j < 4; ++j) v[j] = fmaxf(hseg[s][j] * invn, 0.f);
        uint2 o;
        o.x = (unsigned)f2bf(v[0]) | ((unsigned)f2bf(v[1]) << 16);
        o.y = (unsigned)f2bf(v[2]) | ((unsigned)f2bf(v[3]) << 16);
        *(uint2*)(hr + s * 256 + l * 4) = o;
        #pragma unroll
        for (int j = 0; j < 4; ++j) {
            lpart[w][       s * 256 + l * 4 + j] = v[j];
            lpart[w][1024 + s * 256 + l * 4 + j] = v[j] * v[j];
        }
    }
    __syncthreads();
    float* sb = &sums[(blockIdx.x & (NREP - 1)) * 2048];
    for (int c = t; c < 2048; c += 256)
        atomicAdd(&sb[c], lpart[0][c] + lpart[1][c] + lpart[2][c] + lpart[3][c]);
}

__global__ __launch_bounds__(256) void k3_coef(
    const float* __restrict__ sums, const float* __restrict__ gamma,
    const float* __restrict__ beta, float* __restrict__ cA, float* __restrict__ cB)
{
    int c = blockIdx.x * 256 + threadIdx.x;
    float s = 0.f, s2 = 0.f;
    #pragma unroll
    for (int rep = 0; rep < NREP; ++rep) {
        s  += sums[rep * 2048 + c];
        s2 += sums[rep * 2048 + 1024 + c];
    }
    float mu  = s  * (1.f / 4096.f);
    float var = s2 * (1.f / 4096.f) - mu * mu;
    float a = gamma[c] / sqrtf(var + 1e-5f);
    cA[c] = a;
    cB[c] = beta[c] - mu * a;
}

__global__ __launch_bounds__(256) void k4_apply(
    const unsigned short* __restrict__ hbuf, const float* __restrict__ cA,
    const float* __restrict__ cB, float* __restrict__ out)
{
    int gid = blockIdx.x * 256 + threadIdx.x;
    int c0 = (gid & 255) * 4;
    uint2 hd = *(const uint2*)(hbuf + (unsigned)gid * 4u);
    float4 a = *(const float4*)&cA[c0];
    float4 b = *(const float4*)&cB[c0];
    float4 o;
    o.x = bflo(hd.x) * a.x + b.x;  o.y = bfhi(hd.x) * a.y + b.y;
    o.z = bflo(hd.y) * a.z + b.z;  o.w = bfhi(hd.y) * a.w + b.w;
    *(float4*)&out[(unsigned)gid * 4u] = o;
}

extern "C" void kernel_launch(void* const* d_in, const int* in_sizes, int n_in,
                              void* d_out, int out_size, void* d_ws, size_t ws_size,
                              hipStream_t stream)
{
    const float* x     = (const float*)d_in[0];
    const int*   idx1  = (const int*)  d_in[1];
    const int*   idx2  = (const int*)  d_in[2];
    const int*   idx3  = (const int*)  d_in[3];
    const float* Wx    = (const float*)d_in[4];
    const float* bx    = (const float*)d_in[5];
    const float* Wn    = (const float*)d_in[6];
    const float* bn    = (const float*)d_in[7];
    const float* gamma = (const float*)d_in[8];
    const float* beta  = (const float*)d_in[9];

    char* ws = (char*)d_ws;
    unsigned short* xWx  = (unsigned short*)(ws + OFF_XWX);
    unsigned short* xWn  = (unsigned short*)(ws + OFF_XWN);
    float*          sums = (float*)         (ws + OFF_SUMS);
    float*          outp = (float*)d_out;

    void* args[] = { (void*)&x, (void*)&idx1, (void*)&idx2, (void*)&idx3,
                     (void*)&Wx, (void*)&bx, (void*)&Wn, (void*)&bn,
                     (void*)&gamma, (void*)&beta,
                     (void*)&xWx, (void*)&xWn, (void*)&sums, (void*)&outp };
    hipError_t err = hipLaunchCooperativeKernel((void*)fused_sage, dim3(1024),
                                                dim3(256), args, 0, stream);
    if (err != hipSuccess) {
        // fallback: proven 5-kernel pipeline (r5)
        unsigned short* Wcat = (unsigned short*)(ws + OFF_WCAT);
        unsigned short* hbuf = (unsigned short*)(ws + OFF_HBUF);
        float*          cA   = (float*)         (ws + OFF_COEFA);
        float*          cB   = (float*)         (ws + OFF_COEFB);
        k0_convert<<<128, 256, 0, stream>>>(Wx, Wn, Wcat);
        k1_gemm<<<dim3(64, 8), 256, 0, stream>>>(x, Wcat, bx, xWx, xWn);
        hipMemsetAsync(sums, 0, NREP * 2048 * sizeof(float), stream);
        k2_rows<<<1024, 256, 0, stream>>>(xWx, xWn, idx1, idx2, idx3, bn, hbuf, sums);
        k3_coef<<<4, 256, 0, stream>>>(sums, gamma, beta, cA, cB);
        k4_apply<<<4096, 256, 0, stream>>>(hbuf, cA, cB, outp);
    }
}

// Round 8
// 128.654 us; speedup vs baseline: 2.9923x; 2.9923x over previous
//
#include <hip/hip_runtime.h>

// ---------------------------------------------------------------------------
// BatchedGraphSAGE, 3-dispatch pipeline (coop grid.sync abandoned: r7 showed
// cg::this_grid().sync() costs ~125us each on 8-XCD MI355X).
// mean(gather(x)) @ W^T == mean(gather(x @ W^T)): project once, gather the
// 2 MB bf16 projected tensor (L2-resident).
// kA: GEMM x(f32)@[Wx;Wn]^T with in-register W->bf16 convert; bias folded;
//     LDS-staged coalesced bf16 epilogue; blocks 0..15 zero BN sums.
// kB: wave-per-row gather-mean + l2norm + relu -> h(bf16) + BN partials into
//     16 replicated atomic buffers (1024 blocks, proven in r5).
// kC: per-thread fold of 16 partials (own 4 channels) + BN apply, 4 rows per
//     block, coalesced float4 out.
// ---------------------------------------------------------------------------

typedef short  s16x8 __attribute__((ext_vector_type(8)));
typedef float  f32x4 __attribute__((ext_vector_type(4)));

#define NREP 16

// ws layout (bytes), total ~12.3 MB
#define OFF_XWX    (0u)            // xWx  [4096][256] bf16 : 2 MB (bias added)
#define OFF_XWN    (2097152u)      // xWn  [4096][256] bf16 : 2 MB
#define OFF_SUMS   (4194304u)      // sums [16][2048] f32   : 128 KB
#define OFF_HBUF   (4325376u)      // h    [4096][1024] bf16: 8 MB

__device__ __forceinline__ unsigned short f2bf(float f) {
    unsigned int u = __float_as_uint(f);
    u = (u + 0x7FFFu + ((u >> 16) & 1u)) >> 16;          // RNE
    return (unsigned short)u;
}
__device__ __forceinline__ float bflo(unsigned int d) {
    return __uint_as_float(d << 16);
}
__device__ __forceinline__ float bfhi(unsigned int d) {
    return __uint_as_float(d & 0xFFFF0000u);
}
__device__ __forceinline__ s16x8 cvt_frag(const float* p) {
    float4 a0 = *(const float4*)p;
    float4 a1 = *(const float4*)(p + 4);
    s16x8 a;
    a[0]=(short)f2bf(a0.x); a[1]=(short)f2bf(a0.y);
    a[2]=(short)f2bf(a0.z); a[3]=(short)f2bf(a0.w);
    a[4]=(short)f2bf(a1.x); a[5]=(short)f2bf(a1.y);
    a[6]=(short)f2bf(a1.z); a[7]=(short)f2bf(a1.w);
    return a;
}

// kA: GEMM, 64 rows x 32 cols per block, 1024 blocks. W converted in-register
// (verified in r7's Phase A). Also zeroes the BN partial buffers.
__global__ __launch_bounds__(256) void kA_gemm(
    const float* __restrict__ x,
    const float* __restrict__ Wx, const float* __restrict__ bx,
    const float* __restrict__ Wn,
    unsigned short* __restrict__ xWx, unsigned short* __restrict__ xWn,
    float* __restrict__ sums)
{
    __shared__ unsigned short stage[64 * 32];            // 4 KB
    const int t = threadIdx.x, w = t >> 6, l = t & 63;
    const int l15 = l & 15, lhi = l >> 4;
    const int bid = blockIdx.x;
    const int rowTile = bid >> 4;                        // 0..63
    const int colTile = bid & 15;                        // 0..15
    const int rowBase = rowTile * 64 + w * 16;
    const int colBase = colTile * 32;
    const bool isX = (colTile < 8);
    const float* Wmat = isX ? Wx : Wn;
    const int wrow0 = colBase - (isX ? 0 : 256);         // 0..224 within Wmat

    f32x4 acc[2] = {};
    const float* ap  = &x[(rowBase + l15) * 256 + lhi * 8];
    const float* wp0 = &Wmat[(wrow0 +      l15) * 256 + lhi * 8];
    const float* wp1 = &Wmat[(wrow0 + 16 + l15) * 256 + lhi * 8];
    #pragma unroll
    for (int kk = 0; kk < 256; kk += 32) {
        s16x8 a  = cvt_frag(ap  + kk);
        s16x8 b0 = cvt_frag(wp0 + kk);
        s16x8 b1 = cvt_frag(wp1 + kk);
        acc[0] = __builtin_amdgcn_mfma_f32_16x16x32_bf16(a, b0, acc[0], 0, 0, 0);
        acc[1] = __builtin_amdgcn_mfma_f32_16x16x32_bf16(a, b1, acc[1], 0, 0, 0);
    }
    if (bid < NREP) {                                    // zero BN partials
        float4 z = {0.f, 0.f, 0.f, 0.f};
        *(float4*)&sums[bid * 2048 + t * 4]        = z;
        *(float4*)&sums[bid * 2048 + 1024 + t * 4] = z;
    }
    // C/D layout: col = lane&15, row = (lane>>4)*4 + reg
    const int row0l = w * 16 + lhi * 4;
    #pragma unroll
    for (int c = 0; c < 2; ++c) {
        float badd = isX ? bx[colBase + c * 16 + l15] : 0.f;
        #pragma unroll
        for (int r = 0; r < 4; ++r)
            stage[(row0l + r) * 32 + c * 16 + l15] = f2bf(acc[c][r] + badd);
    }
    __syncthreads();
    {
        const int rl = t >> 2, seg = t & 3;              // 64 rows x 4 segs
        uint4 v = *(const uint4*)&stage[rl * 32 + seg * 8];
        unsigned short* dst = isX ? xWx : xWn;
        *(uint4*)&dst[(rowTile * 64 + rl) * 256 + wrow0 + seg * 8] = v;
    }
}

// kB: wave-per-row gather + l2norm + relu -> h bf16; BN partials ->
// 16 replicated atomic buffers. 1024 blocks (4/CU). Proven in r5.
__global__ __launch_bounds__(256) void kB_rows(
    const unsigned short* __restrict__ xWx, const unsigned short* __restrict__ xWn,
    const int* __restrict__ idx1, const int* __restrict__ idx2,
    const int* __restrict__ idx3, const float* __restrict__ bn,
    unsigned short* __restrict__ hbuf, float* __restrict__ sums)
{
    __shared__ int   lidx[4][96];
    __shared__ float lpart[4][2048];
    const int t = threadIdx.x, w = t >> 6, l = t & 63;
    const int r = blockIdx.x * 4 + w;
    const int b = r >> 9, n = r & 511;

    if (l < 32) {
        lidx[w][l]      = idx1[n * 32 + l];
        lidx[w][64 + l] = idx3[n * 32 + l];
    } else {
        lidx[w][l]      = idx2[n * 32 + (l & 31)];
    }
    __syncthreads();

    const float4 bnv = *(const float4*)&bn[l * 4];
    const unsigned short* basep = &xWn[(unsigned)b * (512u * 256u)];
    f32x4 m1 = {}, m2 = {}, m3 = {};
    #pragma unroll
    for (int k = 0; k < 32; ++k) {
        uint2 d = *(const uint2*)(basep + lidx[w][k] * 256 + l * 4);
        m1[0] += bflo(d.x); m1[1] += bfhi(d.x);
        m1[2] += bflo(d.y); m1[3] += bfhi(d.y);
    }
    #pragma unroll
    for (int k = 0; k < 32; ++k) {
        uint2 d = *(const uint2*)(basep + lidx[w][32 + k] * 256 + l * 4);
        m2[0] += bflo(d.x); m2[1] += bfhi(d.x);
        m2[2] += bflo(d.y); m2[3] += bfhi(d.y);
    }
    #pragma unroll
    for (int k = 0; k < 32; ++k) {
        uint2 d = *(const uint2*)(basep + lidx[w][64 + k] * 256 + l * 4);
        m3[0] += bflo(d.x); m3[1] += bfhi(d.x);
        m3[2] += bflo(d.y); m3[3] += bfhi(d.y);
    }

    uint2 hd = *(const uint2*)(xWx + r * 256 + l * 4);   // bias pre-added
    f32x4 hseg[4];
    hseg[0][0] = bflo(hd.x); hseg[0][1] = bfhi(hd.x);
    hseg[0][2] = bflo(hd.y); hseg[0][3] = bfhi(hd.y);
    #pragma unroll
    for (int j = 0; j < 4; ++j) {
        hseg[1][j] = m1[j] * (1.f / 32.f) + bnv[j];
        hseg[2][j] = m2[j] * (1.f / 32.f) + bnv[j];
        hseg[3][j] = m3[j] * (1.f / 32.f) + bnv[j];
    }
    float p = 0.f;
    #pragma unroll
    for (int s = 0; s < 4; ++s)
        #pragma unroll
        for (int j = 0; j < 4; ++j) p += hseg[s][j] * hseg[s][j];
    #pragma unroll
    for (int m = 32; m > 0; m >>= 1) p += __shfl_xor(p, m);
    const float invn = 1.0f / fmaxf(sqrtf(p), 1e-12f);

    unsigned short* hr = &hbuf[(unsigned)r * 1024u];
    #pragma unroll
    for (int s = 0; s < 4; ++s) {
        f32x4 v;
        #pragma unroll
        for (int j = 0; j < 4; ++j) v[j] = fmaxf(hseg[s][j] * invn, 0.f);
        uint2 o;
        o.x = (unsigned)f2bf(v[0]) | ((unsigned)f2bf(v[1]) << 16);
        o.y = (unsigned)f2bf(v[2]) | ((unsigned)f2bf(v[3]) << 16);
        *(uint2*)(hr + s * 256 + l * 4) = o;
        #pragma unroll
        for (int j = 0; j < 4; ++j) {
            lpart[w][       s * 256 + l * 4 + j] = v[j];
            lpart[w][1024 + s * 256 + l * 4 + j] = v[j] * v[j];
        }
    }
    __syncthreads();
    float* sb = &sums[(blockIdx.x & (NREP - 1)) * 2048];
    for (int c = t; c < 2048; c += 256)
        atomicAdd(&sb[c], lpart[0][c] + lpart[1][c] + lpart[2][c] + lpart[3][c]);
}

// kC: fold 16 replicated partials for this thread's 4 channels -> BN coefs,
// then apply over 4 rows. 1024 blocks; sums (128 KB) is L2-resident.
__global__ __launch_bounds__(256) void kC_apply(
    const float* __restrict__ sums, const float* __restrict__ gamma,
    const float* __restrict__ beta, const unsigned short* __restrict__ hbuf,
    float* __restrict__ out)
{
    const int t = threadIdx.x;
    const int c0 = t * 4;
    f32x4 s = {}, q = {};
    #pragma unroll
    for (int rep = 0; rep < NREP; ++rep) {
        float4 a  = *(const float4*)&sums[rep * 2048 + c0];
        float4 b2 = *(const float4*)&sums[rep * 2048 + 1024 + c0];
        s[0] += a.x;  s[1] += a.y;  s[2] += a.z;  s[3] += a.w;
        q[0] += b2.x; q[1] += b2.y; q[2] += b2.z; q[3] += b2.w;
    }
    float4 g  = *(const float4*)&gamma[c0];
    float4 be = *(const float4*)&beta[c0];
    const float gg[4] = {g.x, g.y, g.z, g.w};
    const float bb[4] = {be.x, be.y, be.z, be.w};
    f32x4 A, Bc;
    #pragma unroll
    for (int j = 0; j < 4; ++j) {
        float mu  = s[j] * (1.f / 4096.f);
        float var = q[j] * (1.f / 4096.f) - mu * mu;
        A[j]  = gg[j] / sqrtf(var + 1e-5f);
        Bc[j] = bb[j] - mu * A[j];
    }
    #pragma unroll
    for (int r2 = 0; r2 < 4; ++r2) {
        const unsigned row = blockIdx.x * 4 + r2;
        uint2 hd = *(const uint2*)(hbuf + row * 1024u + c0);
        float4 o;
        o.x = bflo(hd.x) * A[0] + Bc[0];
        o.y = bfhi(hd.x) * A[1] + Bc[1];
        o.z = bflo(hd.y) * A[2] + Bc[2];
        o.w = bfhi(hd.y) * A[3] + Bc[3];
        *(float4*)&out[row * 1024u + c0] = o;
    }
}

extern "C" void kernel_launch(void* const* d_in, const int* in_sizes, int n_in,
                              void* d_out, int out_size, void* d_ws, size_t ws_size,
                              hipStream_t stream)
{
    const float* x     = (const float*)d_in[0];
    const int*   idx1  = (const int*)  d_in[1];
    const int*   idx2  = (const int*)  d_in[2];
    const int*   idx3  = (const int*)  d_in[3];
    const float* Wx    = (const float*)d_in[4];
    const float* bx    = (const float*)d_in[5];
    const float* Wn    = (const float*)d_in[6];
    const float* bn    = (const float*)d_in[7];
    const float* gamma = (const float*)d_in[8];
    const float* beta  = (const float*)d_in[9];

    char* ws = (char*)d_ws;
    unsigned short* xWx  = (unsigned short*)(ws + OFF_XWX);
    unsigned short* xWn  = (unsigned short*)(ws + OFF_XWN);
    float*          sums = (float*)         (ws + OFF_SUMS);
    unsigned short* hbuf = (unsigned short*)(ws + OFF_HBUF);

    kA_gemm<<<1024, 256, 0, stream>>>(x, Wx, bx, Wn, xWx, xWn, sums);
    kB_rows<<<1024, 256, 0, stream>>>(xWx, xWn, idx1, idx2, idx3, bn, hbuf, sums);
    kC_apply<<<1024, 256, 0, stream>>>(sums, gamma, beta, hbuf, (float*)d_out);
}